// Round 1
// baseline (607.000 us; speedup 1.0000x reference)
//
#include <hip/hip_runtime.h>

#define T_TOK 8192
#define DIM 1024
#define HID 2048
#define NE 8
#define TK 16384   // T_TOK * 2

typedef __bf16 bf16x8 __attribute__((ext_vector_type(8)));
typedef float f32x4 __attribute__((ext_vector_type(4)));

// ---------------- ws layout (bytes) ----------------
#define OFF_XN      0UL            // T*D*2            = 16,777,216
#define OFF_W1B     16777216UL     // E*H*D*2          = 33,554,432
#define OFF_W2B     50331648UL     // E*D*H*2          = 33,554,432
#define OFF_H       83886080UL     // TK*H*2           = 67,108,864
#define OFF_ATOK    150994944UL    // TK*4
#define OFF_AGATE   151060480UL    // TK*4
#define OFF_TOPI    151126016UL    // T*4
#define OFF_GATES   151158784UL    // T*8 (float2)
#define OFF_CPART   151224320UL    // 64*8*4
#define OFF_PPART   151226368UL    // 64*8*4
#define OFF_COUNTS  151228416UL    // 8*4
#define OFF_OFFS    151228448UL
#define OFF_CNT2    151228480UL
#define OFF_NT      151228512UL
#define OFF_TMAP    151228544UL    // 272*16

__device__ __forceinline__ unsigned short f2bf(float f) {
    union { float fv; unsigned u; } q; q.fv = f;
    unsigned r = q.u + 0x7fffu + ((q.u >> 16) & 1u);
    return (unsigned short)(r >> 16);
}

__device__ __forceinline__ float gelu_exact(float x) {
    return 0.5f * x * (1.0f + erff(x * 0.70710678118654752440f));
}

// -------- fp32 -> bf16 conversion (weights) --------
__global__ __launch_bounds__(256) void convert_kernel(const float4* __restrict__ src,
                                                      ushort4* __restrict__ dst, int n4) {
    int i = blockIdx.x * 256 + threadIdx.x;
    if (i < n4) {
        float4 f = src[i];
        ushort4 u;
        u.x = f2bf(f.x); u.y = f2bf(f.y); u.z = f2bf(f.z); u.w = f2bf(f.w);
        dst[i] = u;
    }
}

// -------- fused LayerNorm + router --------
__global__ __launch_bounds__(256) void ln_router_kernel(
    const float* __restrict__ x, const float* __restrict__ gw,
    const float* __restrict__ gamma, const float* __restrict__ beta,
    unsigned short* __restrict__ xnb, int* __restrict__ top_idx,
    float2* __restrict__ gates, int* __restrict__ counts_partial,
    float* __restrict__ probs_partial)
{
    __shared__ float sprob[8];
    __shared__ int scnt[8];
    int tid = threadIdx.x;
    if (tid < 8) { sprob[tid] = 0.f; scnt[tid] = 0; }
    __syncthreads();

    int wave = tid >> 6, lane = tid & 63;
    int t = blockIdx.x * 4 + wave;
    const float* xt = x + (size_t)t * DIM;

    float v[16];
    float s = 0.f, sq = 0.f;
#pragma unroll
    for (int j = 0; j < 4; j++) {
        float4 f = *(const float4*)(xt + j * 256 + lane * 4);
        v[4*j+0] = f.x; v[4*j+1] = f.y; v[4*j+2] = f.z; v[4*j+3] = f.w;
        s += f.x + f.y + f.z + f.w;
        sq += f.x*f.x + f.y*f.y + f.z*f.z + f.w*f.w;
    }
#pragma unroll
    for (int o = 32; o > 0; o >>= 1) { s += __shfl_xor(s, o); sq += __shfl_xor(sq, o); }
    float mean = s * (1.0f / DIM);
    float var = sq * (1.0f / DIM) - mean * mean;
    float rstd = rsqrtf(var + 1e-5f);

#pragma unroll
    for (int j = 0; j < 4; j++) {
        float4 gm = *(const float4*)(gamma + j * 256 + lane * 4);
        float4 bt = *(const float4*)(beta + j * 256 + lane * 4);
        float x0 = (v[4*j+0] - mean) * rstd * gm.x + bt.x;
        float x1 = (v[4*j+1] - mean) * rstd * gm.y + bt.y;
        float x2 = (v[4*j+2] - mean) * rstd * gm.z + bt.z;
        float x3 = (v[4*j+3] - mean) * rstd * gm.w + bt.w;
        ushort4 u; u.x = f2bf(x0); u.y = f2bf(x1); u.z = f2bf(x2); u.w = f2bf(x3);
        *(ushort4*)(xnb + (size_t)t * DIM + j * 256 + lane * 4) = u;
        v[4*j+0] = x0; v[4*j+1] = x1; v[4*j+2] = x2; v[4*j+3] = x3;
    }

    // router logits in fp64 (top-k stability vs reference)
    double part[8];
#pragma unroll
    for (int e = 0; e < 8; e++) {
        double p = 0.0;
        const float* ge = gw + (size_t)e * DIM;
#pragma unroll
        for (int j = 0; j < 4; j++) {
            float4 g = *(const float4*)(ge + j * 256 + lane * 4);
            p += (double)v[4*j+0] * (double)g.x;
            p += (double)v[4*j+1] * (double)g.y;
            p += (double)v[4*j+2] * (double)g.z;
            p += (double)v[4*j+3] * (double)g.w;
        }
        part[e] = p;
    }
#pragma unroll
    for (int o = 32; o > 0; o >>= 1)
#pragma unroll
        for (int e = 0; e < 8; e++) part[e] += __shfl_xor(part[e], o);

    if (lane == 0) {
        double l0 = -1e300; int e0 = -1;
#pragma unroll
        for (int e = 0; e < 8; e++) if (part[e] > l0) { l0 = part[e]; e0 = e; }
        double l1 = -1e300; int e1 = -1;
#pragma unroll
        for (int e = 0; e < 8; e++) if (e != e0 && part[e] > l1) { l1 = part[e]; e1 = e; }
        float d = expf((float)(l1 - l0));
        float g0 = 1.0f / (1.0f + d);
        float g1 = d / (1.0f + d);
        top_idx[t] = e0 | (e1 << 8);
        gates[t] = make_float2(g0, g1);
        atomicAdd(&scnt[e0], 1);
        atomicAdd(&scnt[e1], 1);
        float pe[8]; float sum = 0.f;
#pragma unroll
        for (int e = 0; e < 8; e++) { pe[e] = expf((float)(part[e] - l0)); sum += pe[e]; }
        float inv = 1.0f / sum;
#pragma unroll
        for (int e = 0; e < 8; e++) atomicAdd(&sprob[e], pe[e] * inv);
    }
    __syncthreads();
    if (tid < 8) {
        int bin = (blockIdx.x & 63) * 8 + tid;
        atomicAdd(&probs_partial[bin], sprob[tid]);
        atomicAdd(&counts_partial[bin], scnt[tid]);
    }
}

// -------- finalize: counts, offsets, tile map, lb loss --------
__global__ void finalize_kernel(const int* __restrict__ counts_partial,
                                const float* __restrict__ probs_partial,
                                int* __restrict__ counts, int* __restrict__ offsets,
                                int* __restrict__ cnt2, int* __restrict__ ntiles,
                                int4* __restrict__ tile_map, float* __restrict__ lb_out)
{
    if (threadIdx.x != 0 || blockIdx.x != 0) return;
    int c[8]; float p[8];
    for (int e = 0; e < 8; e++) { c[e] = 0; p[e] = 0.f; }
    for (int b = 0; b < 64; b++)
        for (int e = 0; e < 8; e++) { c[e] += counts_partial[b*8+e]; p[e] += probs_partial[b*8+e]; }
    int off = 0, nt = 0;
    for (int e = 0; e < 8; e++) {
        offsets[e] = off; counts[e] = c[e]; cnt2[e] = 0;
        for (int m0 = 0; m0 < c[e]; m0 += 64) tile_map[nt++] = make_int4(e, m0, off, c[e]);
        off += c[e];
    }
    *ntiles = nt;
    float avg[8]; float m = 0.f;
    for (int e = 0; e < 8; e++) { avg[e] = p[e] / (float)T_TOK; m += avg[e]; }
    m *= (1.0f / 8.0f);
    float var = 0.f;
    for (int e = 0; e < 8; e++) { float d = avg[e] - m; var += d * d; }
    var *= (1.0f / 7.0f);
    float mm = m + 1e-6f;
    lb_out[0] = (var / (mm * mm)) * 0.01f;
}

// -------- placement: build per-expert token lists --------
__global__ __launch_bounds__(256) void placement_kernel(
    const int* __restrict__ top_idx, const float2* __restrict__ gates,
    const int* __restrict__ offsets, int* __restrict__ cnt2,
    int* __restrict__ atok, float* __restrict__ agate)
{
    __shared__ int lcnt[8];
    __shared__ int lbase[8];
    __shared__ int ltok[4096];
    __shared__ float lgate[4096];
    int tid = threadIdx.x;
    if (tid < 8) lcnt[tid] = 0;
    __syncthreads();
    int t = blockIdx.x * 256 + tid;
    int pk = top_idx[t];
    float2 g = gates[t];
    int e0 = pk & 255, e1 = (pk >> 8) & 255;
    int p0 = atomicAdd(&lcnt[e0], 1); ltok[e0*512+p0] = t; lgate[e0*512+p0] = g.x;
    int p1 = atomicAdd(&lcnt[e1], 1); ltok[e1*512+p1] = t; lgate[e1*512+p1] = g.y;
    __syncthreads();
    if (tid < 8) lbase[tid] = offsets[tid] + atomicAdd(&cnt2[tid], lcnt[tid]);
    __syncthreads();
    for (int e = 0; e < 8; e++) {
        int c = lcnt[e], b = lbase[e];
        for (int i = tid; i < c; i += 256) { atok[b+i] = ltok[e*512+i]; agate[b+i] = lgate[e*512+i]; }
    }
}

// -------- GEMM1: h = gelu(xn[tok] @ w1[e]^T), store bf16 --------
__global__ __launch_bounds__(256) void gemm1_kernel(
    const unsigned short* __restrict__ xnb, const unsigned short* __restrict__ w1b,
    unsigned short* __restrict__ hbuf, const int* __restrict__ atok,
    const int4* __restrict__ tile_map, const int* __restrict__ ntiles)
{
    if ((int)blockIdx.x >= *ntiles) return;
    int4 tm = tile_map[blockIdx.x];
    int e = tm.x, m0 = tm.y, base = tm.z, cnt = tm.w;
    int n0 = blockIdx.y * 64;

    __shared__ unsigned short As[64 * 40];
    __shared__ unsigned short Bs[64 * 40];

    int tid = threadIdx.x;
    int row = tid >> 2, seg = tid & 3;
    int aidx = base + m0 + row;
    if (m0 + row >= cnt) aidx = base;
    int tok = atok[aidx];
    const unsigned short* aptr = xnb + (size_t)tok * DIM + seg * 8;
    const unsigned short* bptr = w1b + ((size_t)e * HID + (n0 + row)) * DIM + seg * 8;

    int lane = tid & 63, wave = tid >> 6;
    int wm = (wave >> 1) * 32, wn = (wave & 1) * 32;
    int quad = lane >> 4, col = lane & 15;
    f32x4 acc[2][2] = {};
    int aoff = (wm + col) * 40 + quad * 8;
    int boff = (wn + col) * 40 + quad * 8;
    int soff = row * 40 + seg * 8;

    for (int k0 = 0; k0 < DIM; k0 += 32) {
        uint4 av = *(const uint4*)(aptr + k0);
        uint4 bv = *(const uint4*)(bptr + k0);
        __syncthreads();
        *(uint4*)&As[soff] = av;
        *(uint4*)&Bs[soff] = bv;
        __syncthreads();
        bf16x8 a0 = *(const bf16x8*)&As[aoff];
        bf16x8 a1 = *(const bf16x8*)&As[aoff + 16 * 40];
        bf16x8 b0 = *(const bf16x8*)&Bs[boff];
        bf16x8 b1 = *(const bf16x8*)&Bs[boff + 16 * 40];
        acc[0][0] = __builtin_amdgcn_mfma_f32_16x16x32_bf16(a0, b0, acc[0][0], 0, 0, 0);
        acc[0][1] = __builtin_amdgcn_mfma_f32_16x16x32_bf16(a0, b1, acc[0][1], 0, 0, 0);
        acc[1][0] = __builtin_amdgcn_mfma_f32_16x16x32_bf16(a1, b0, acc[1][0], 0, 0, 0);
        acc[1][1] = __builtin_amdgcn_mfma_f32_16x16x32_bf16(a1, b1, acc[1][1], 0, 0, 0);
    }

#pragma unroll
    for (int mi = 0; mi < 2; mi++)
#pragma unroll
        for (int i = 0; i < 4; i++) {
            int m = wm + mi * 16 + quad * 4 + i;
            if (m0 + m < cnt) {
                size_t hrow = (size_t)(base + m0 + m) * HID + n0;
#pragma unroll
                for (int ni = 0; ni < 2; ni++) {
                    float vv = gelu_exact(acc[mi][ni][i]);
                    hbuf[hrow + wn + ni * 16 + col] = f2bf(vv);
                }
            }
        }
}

// -------- GEMM2: out[tok] += gate * (h @ w2[e]^T) --------
__global__ __launch_bounds__(256) void gemm2_kernel(
    const unsigned short* __restrict__ hbuf, const unsigned short* __restrict__ w2b,
    float* __restrict__ out, const int* __restrict__ atok, const float* __restrict__ agate,
    const int4* __restrict__ tile_map, const int* __restrict__ ntiles)
{
    if ((int)blockIdx.x >= *ntiles) return;
    int4 tm = tile_map[blockIdx.x];
    int e = tm.x, m0 = tm.y, base = tm.z, cnt = tm.w;
    int n0 = blockIdx.y * 64;

    __shared__ unsigned short As[64 * 40];
    __shared__ unsigned short Bs[64 * 40];

    int tid = threadIdx.x;
    int row = tid >> 2, seg = tid & 3;
    int arow = base + m0 + row;
    if (m0 + row >= cnt) arow = base;
    const unsigned short* aptr = hbuf + (size_t)arow * HID + seg * 8;
    const unsigned short* bptr = w2b + ((size_t)e * DIM + (n0 + row)) * HID + seg * 8;

    int lane = tid & 63, wave = tid >> 6;
    int wm = (wave >> 1) * 32, wn = (wave & 1) * 32;
    int quad = lane >> 4, col = lane & 15;
    f32x4 acc[2][2] = {};
    int aoff = (wm + col) * 40 + quad * 8;
    int boff = (wn + col) * 40 + quad * 8;
    int soff = row * 40 + seg * 8;

    for (int k0 = 0; k0 < HID; k0 += 32) {
        uint4 av = *(const uint4*)(aptr + k0);
        uint4 bv = *(const uint4*)(bptr + k0);
        __syncthreads();
        *(uint4*)&As[soff] = av;
        *(uint4*)&Bs[soff] = bv;
        __syncthreads();
        bf16x8 a0 = *(const bf16x8*)&As[aoff];
        bf16x8 a1 = *(const bf16x8*)&As[aoff + 16 * 40];
        bf16x8 b0 = *(const bf16x8*)&Bs[boff];
        bf16x8 b1 = *(const bf16x8*)&Bs[boff + 16 * 40];
        acc[0][0] = __builtin_amdgcn_mfma_f32_16x16x32_bf16(a0, b0, acc[0][0], 0, 0, 0);
        acc[0][1] = __builtin_amdgcn_mfma_f32_16x16x32_bf16(a0, b1, acc[0][1], 0, 0, 0);
        acc[1][0] = __builtin_amdgcn_mfma_f32_16x16x32_bf16(a1, b0, acc[1][0], 0, 0, 0);
        acc[1][1] = __builtin_amdgcn_mfma_f32_16x16x32_bf16(a1, b1, acc[1][1], 0, 0, 0);
    }

#pragma unroll
    for (int mi = 0; mi < 2; mi++)
#pragma unroll
        for (int i = 0; i < 4; i++) {
            int m = wm + mi * 16 + quad * 4 + i;
            if (m0 + m < cnt) {
                int ai = base + m0 + m;
                int tok = atok[ai];
                float g = agate[ai];
                float* orow = out + (size_t)tok * DIM + n0;
#pragma unroll
                for (int ni = 0; ni < 2; ni++) {
                    atomicAdd(&orow[wn + ni * 16 + col], g * acc[mi][ni][i]);
                }
            }
        }
}

extern "C" void kernel_launch(void* const* d_in, const int* in_sizes, int n_in,
                              void* d_out, int out_size, void* d_ws, size_t ws_size,
                              hipStream_t stream) {
    (void)in_sizes; (void)n_in; (void)out_size; (void)ws_size;
    const float* x     = (const float*)d_in[0];
    const float* gw    = (const float*)d_in[1];
    const float* w1    = (const float*)d_in[2];
    const float* w2    = (const float*)d_in[3];
    const float* gamma = (const float*)d_in[4];
    const float* beta  = (const float*)d_in[5];
    float* out = (float*)d_out;
    char* ws = (char*)d_ws;

    unsigned short* xnb  = (unsigned short*)(ws + OFF_XN);
    unsigned short* w1b  = (unsigned short*)(ws + OFF_W1B);
    unsigned short* w2b  = (unsigned short*)(ws + OFF_W2B);
    unsigned short* hbuf = (unsigned short*)(ws + OFF_H);
    int*    atok    = (int*)(ws + OFF_ATOK);
    float*  agate   = (float*)(ws + OFF_AGATE);
    int*    topi    = (int*)(ws + OFF_TOPI);
    float2* gates   = (float2*)(ws + OFF_GATES);
    int*    cpart   = (int*)(ws + OFF_CPART);
    float*  ppart   = (float*)(ws + OFF_PPART);
    int*    counts  = (int*)(ws + OFF_COUNTS);
    int*    offsets = (int*)(ws + OFF_OFFS);
    int*    cnt2    = (int*)(ws + OFF_CNT2);
    int*    ntiles  = (int*)(ws + OFF_NT);
    int4*   tmap    = (int4*)(ws + OFF_TMAP);

    // zero the partial histograms (cpart+ppart contiguous 4 KB)
    hipMemsetAsync(ws + OFF_CPART, 0, 4096, stream);
    // residual: out = x
    hipMemcpyAsync(d_out, (const void*)x, (size_t)T_TOK * DIM * sizeof(float),
                   hipMemcpyDeviceToDevice, stream);

    convert_kernel<<<16384, 256, 0, stream>>>((const float4*)w1, (ushort4*)w1b, (NE*HID*DIM)/4);
    convert_kernel<<<16384, 256, 0, stream>>>((const float4*)w2, (ushort4*)w2b, (NE*DIM*HID)/4);

    ln_router_kernel<<<T_TOK / 4, 256, 0, stream>>>(x, gw, gamma, beta, xnb, topi, gates, cpart, ppart);
    finalize_kernel<<<1, 64, 0, stream>>>(cpart, ppart, counts, offsets, cnt2, ntiles, tmap,
                                          out + (size_t)T_TOK * DIM);
    placement_kernel<<<T_TOK / 256, 256, 0, stream>>>(topi, gates, offsets, cnt2, atok, agate);

    gemm1_kernel<<<dim3(264, HID / 64), 256, 0, stream>>>(xnb, w1b, hbuf, atok, tmap, ntiles);
    gemm2_kernel<<<dim3(264, DIM / 64), 256, 0, stream>>>(hbuf, w2b, out, atok, agate, tmap, ntiles);
}

// Round 2
// 466.610 us; speedup vs baseline: 1.3009x; 1.3009x over previous
//
#include <hip/hip_runtime.h>

#define T_TOK 8192
#define DIM 1024
#define HID 2048
#define NE 8
#define TK 16384   // T_TOK * 2

typedef __bf16 bf16x8 __attribute__((ext_vector_type(8)));
typedef float f32x4 __attribute__((ext_vector_type(4)));

// ---------------- ws layout (bytes) ----------------
#define OFF_XN      0UL            // T*D*2            = 16,777,216
#define OFF_W1B     16777216UL     // E*H*D*2          = 33,554,432  (reused as ybuf after gemm1)
#define OFF_W2B     50331648UL     // E*D*H*2          = 33,554,432
#define OFF_H       83886080UL     // TK*H*2           = 67,108,864
#define OFF_ATOK    150994944UL    // TK*4
#define OFF_INV     151060480UL    // T*8 (int2)
#define OFF_TOPI    151126016UL    // T*4
#define OFF_GATES   151158784UL    // T*8 (float2)
#define OFF_CPART   151224320UL    // 64*8*4
#define OFF_PPART   151226368UL    // 64*8*4
#define OFF_COUNTS  151228416UL    // 8*4
#define OFF_OFFS    151228448UL
#define OFF_CNT2    151228480UL
#define OFF_NT      151228512UL
#define OFF_TMAP    151228544UL    // 136*16

__device__ __forceinline__ unsigned short f2bf(float f) {
    union { float fv; unsigned u; } q; q.fv = f;
    unsigned r = q.u + 0x7fffu + ((q.u >> 16) & 1u);
    return (unsigned short)(r >> 16);
}

__device__ __forceinline__ float bf2f(unsigned short u) {
    union { unsigned u; float f; } q; q.u = ((unsigned)u) << 16;
    return q.f;
}

__device__ __forceinline__ float gelu_exact(float x) {
    return 0.5f * x * (1.0f + erff(x * 0.70710678118654752440f));
}

// XOR swizzle of 16B segment within a row: breaks the unpadded-LDS 8-way
// bank conflict on ds_read_b128 down to 2-way (free, m136).
__device__ __forceinline__ int sw(int r) { return (r ^ (r >> 2)) & 3; }

// async 16B global -> LDS (global_load_lds_dwordx4); per-lane lds ptr must be
// wave-uniform base + lane*16 (m104/m108).
__device__ __forceinline__ void g2l16(const unsigned short* g, unsigned short* l) {
    __builtin_amdgcn_global_load_lds(
        (const __attribute__((address_space(1))) unsigned int*)g,
        (__attribute__((address_space(3))) unsigned int*)l, 16, 0, 0);
}

// -------- fp32 -> bf16 conversion (weights) --------
__global__ __launch_bounds__(256) void convert_kernel(const float4* __restrict__ src,
                                                      ushort4* __restrict__ dst, int n4) {
    int i = blockIdx.x * 256 + threadIdx.x;
    if (i < n4) {
        float4 f = src[i];
        ushort4 u;
        u.x = f2bf(f.x); u.y = f2bf(f.y); u.z = f2bf(f.z); u.w = f2bf(f.w);
        dst[i] = u;
    }
}

// -------- fused LayerNorm + router --------
__global__ __launch_bounds__(256) void ln_router_kernel(
    const float* __restrict__ x, const float* __restrict__ gw,
    const float* __restrict__ gamma, const float* __restrict__ beta,
    unsigned short* __restrict__ xnb, int* __restrict__ top_idx,
    float2* __restrict__ gates, int* __restrict__ counts_partial,
    float* __restrict__ probs_partial)
{
    __shared__ float sprob[8];
    __shared__ int scnt[8];
    int tid = threadIdx.x;
    if (tid < 8) { sprob[tid] = 0.f; scnt[tid] = 0; }
    __syncthreads();

    int wave = tid >> 6, lane = tid & 63;
    int t = blockIdx.x * 4 + wave;
    const float* xt = x + (size_t)t * DIM;

    float v[16];
    float s = 0.f, sq = 0.f;
#pragma unroll
    for (int j = 0; j < 4; j++) {
        float4 f = *(const float4*)(xt + j * 256 + lane * 4);
        v[4*j+0] = f.x; v[4*j+1] = f.y; v[4*j+2] = f.z; v[4*j+3] = f.w;
        s += f.x + f.y + f.z + f.w;
        sq += f.x*f.x + f.y*f.y + f.z*f.z + f.w*f.w;
    }
#pragma unroll
    for (int o = 32; o > 0; o >>= 1) { s += __shfl_xor(s, o); sq += __shfl_xor(sq, o); }
    float mean = s * (1.0f / DIM);
    float var = sq * (1.0f / DIM) - mean * mean;
    float rstd = rsqrtf(var + 1e-5f);

#pragma unroll
    for (int j = 0; j < 4; j++) {
        float4 gm = *(const float4*)(gamma + j * 256 + lane * 4);
        float4 bt = *(const float4*)(beta + j * 256 + lane * 4);
        float x0 = (v[4*j+0] - mean) * rstd * gm.x + bt.x;
        float x1 = (v[4*j+1] - mean) * rstd * gm.y + bt.y;
        float x2 = (v[4*j+2] - mean) * rstd * gm.z + bt.z;
        float x3 = (v[4*j+3] - mean) * rstd * gm.w + bt.w;
        ushort4 u; u.x = f2bf(x0); u.y = f2bf(x1); u.z = f2bf(x2); u.w = f2bf(x3);
        *(ushort4*)(xnb + (size_t)t * DIM + j * 256 + lane * 4) = u;
        v[4*j+0] = x0; v[4*j+1] = x1; v[4*j+2] = x2; v[4*j+3] = x3;
    }

    // router logits in fp64 (top-k stability vs reference)
    double part[8];
#pragma unroll
    for (int e = 0; e < 8; e++) {
        double p = 0.0;
        const float* ge = gw + (size_t)e * DIM;
#pragma unroll
        for (int j = 0; j < 4; j++) {
            float4 g = *(const float4*)(ge + j * 256 + lane * 4);
            p += (double)v[4*j+0] * (double)g.x;
            p += (double)v[4*j+1] * (double)g.y;
            p += (double)v[4*j+2] * (double)g.z;
            p += (double)v[4*j+3] * (double)g.w;
        }
        part[e] = p;
    }
#pragma unroll
    for (int o = 32; o > 0; o >>= 1)
#pragma unroll
        for (int e = 0; e < 8; e++) part[e] += __shfl_xor(part[e], o);

    if (lane == 0) {
        double l0 = -1e300; int e0 = -1;
#pragma unroll
        for (int e = 0; e < 8; e++) if (part[e] > l0) { l0 = part[e]; e0 = e; }
        double l1 = -1e300; int e1 = -1;
#pragma unroll
        for (int e = 0; e < 8; e++) if (e != e0 && part[e] > l1) { l1 = part[e]; e1 = e; }
        float d = expf((float)(l1 - l0));
        float g0 = 1.0f / (1.0f + d);
        float g1 = d / (1.0f + d);
        top_idx[t] = e0 | (e1 << 8);
        gates[t] = make_float2(g0, g1);
        atomicAdd(&scnt[e0], 1);
        atomicAdd(&scnt[e1], 1);
        float pe[8]; float sum = 0.f;
#pragma unroll
        for (int e = 0; e < 8; e++) { pe[e] = expf((float)(part[e] - l0)); sum += pe[e]; }
        float inv = 1.0f / sum;
#pragma unroll
        for (int e = 0; e < 8; e++) atomicAdd(&sprob[e], pe[e] * inv);
    }
    __syncthreads();
    if (tid < 8) {
        int bin = (blockIdx.x & 63) * 8 + tid;
        atomicAdd(&probs_partial[bin], sprob[tid]);
        atomicAdd(&counts_partial[bin], scnt[tid]);
    }
}

// -------- finalize: counts, offsets, tile map (128-row tiles), lb loss --------
__global__ void finalize_kernel(const int* __restrict__ counts_partial,
                                const float* __restrict__ probs_partial,
                                int* __restrict__ counts, int* __restrict__ offsets,
                                int* __restrict__ cnt2, int* __restrict__ ntiles,
                                int4* __restrict__ tile_map, float* __restrict__ lb_out)
{
    if (threadIdx.x != 0 || blockIdx.x != 0) return;
    int c[8]; float p[8];
    for (int e = 0; e < 8; e++) { c[e] = 0; p[e] = 0.f; }
    for (int b = 0; b < 64; b++)
        for (int e = 0; e < 8; e++) { c[e] += counts_partial[b*8+e]; p[e] += probs_partial[b*8+e]; }
    int off = 0, nt = 0;
    for (int e = 0; e < 8; e++) {
        offsets[e] = off; counts[e] = c[e]; cnt2[e] = 0;
        for (int m0 = 0; m0 < c[e]; m0 += 128) tile_map[nt++] = make_int4(e, m0, off, c[e]);
        off += c[e];
    }
    *ntiles = nt;
    float avg[8]; float m = 0.f;
    for (int e = 0; e < 8; e++) { avg[e] = p[e] / (float)T_TOK; m += avg[e]; }
    m *= (1.0f / 8.0f);
    float var = 0.f;
    for (int e = 0; e < 8; e++) { float d = avg[e] - m; var += d * d; }
    var *= (1.0f / 7.0f);
    float mm = m + 1e-6f;
    lb_out[0] = (var / (mm * mm)) * 0.01f;
}

// -------- placement: per-expert token lists + inverse slot map --------
__global__ __launch_bounds__(256) void placement_kernel(
    const int* __restrict__ top_idx,
    const int* __restrict__ offsets, int* __restrict__ cnt2,
    int* __restrict__ atok, int2* __restrict__ inv)
{
    __shared__ int lcnt[8];
    __shared__ int lbase[8];
    __shared__ int ltok[4096];
    int tid = threadIdx.x;
    if (tid < 8) lcnt[tid] = 0;
    __syncthreads();
    int t = blockIdx.x * 256 + tid;
    int pk = top_idx[t];
    int e0 = pk & 255, e1 = (pk >> 8) & 255;
    int p0 = atomicAdd(&lcnt[e0], 1); ltok[e0*512+p0] = t;
    int p1 = atomicAdd(&lcnt[e1], 1); ltok[e1*512+p1] = t;
    __syncthreads();
    if (tid < 8) lbase[tid] = offsets[tid] + atomicAdd(&cnt2[tid], lcnt[tid]);
    __syncthreads();
    for (int e = 0; e < 8; e++) {
        int c = lcnt[e], b = lbase[e];
        for (int i = tid; i < c; i += 256) atok[b+i] = ltok[e*512+i];
    }
    inv[t] = make_int2(lbase[e0] + p0, lbase[e1] + p1);
}

// ======== m97-structure grouped GEMM: 128x128 tile, BK=32, global_load_lds ========
// GEMM1: h[slot] = gelu(xn[atok[slot]] @ w1[e]^T)
__global__ __launch_bounds__(256) void gemm1_kernel(
    const unsigned short* __restrict__ xnb, const unsigned short* __restrict__ w1b,
    unsigned short* __restrict__ hbuf, const int* __restrict__ atok,
    const int4* __restrict__ tile_map, const int* __restrict__ ntiles)
{
    if ((int)blockIdx.x >= *ntiles) return;
    int4 tm = tile_map[blockIdx.x];
    int e = tm.x, m0 = tm.y, base = tm.z, cnt = tm.w;
    int n0 = blockIdx.y * 128;

    __shared__ unsigned short As[128 * 32];
    __shared__ unsigned short Bs[128 * 32];

    int tid = threadIdx.x;
    int lane = tid & 63, wave = tid >> 6;

    // staging: chunk c = j*256 + tid -> row = c>>2, seg = c&3; 16B each
    int r0 = tid >> 2, r1 = 64 + (tid >> 2), seg = tid & 3;
    int a0i = base + m0 + r0; if (m0 + r0 >= cnt) a0i = base;
    int a1i = base + m0 + r1; if (m0 + r1 >= cnt) a1i = base;
    int tok0 = atok[a0i], tok1 = atok[a1i];
    const unsigned short* ap0 = xnb + (size_t)tok0 * DIM + (seg ^ sw(r0)) * 8;
    const unsigned short* ap1 = xnb + (size_t)tok1 * DIM + (seg ^ sw(r1)) * 8;
    const unsigned short* bp0 = w1b + ((size_t)e * HID + n0 + r0) * DIM + (seg ^ sw(r0)) * 8;
    const unsigned short* bp1 = w1b + ((size_t)e * HID + n0 + r1) * DIM + (seg ^ sw(r1)) * 8;
    unsigned short* lA0 = &As[(size_t)tid * 8];
    unsigned short* lA1 = &As[(size_t)(256 + tid) * 8];
    unsigned short* lB0 = &Bs[(size_t)tid * 8];
    unsigned short* lB1 = &Bs[(size_t)(256 + tid) * 8];

    int wm = (wave >> 1) * 64, wn = (wave & 1) * 64;
    int quad = lane >> 4, col = lane & 15;
    int aoff[4], boff[4];
#pragma unroll
    for (int i = 0; i < 4; i++) {
        int m = wm + i * 16 + col;
        aoff[i] = m * 32 + ((quad ^ sw(m)) * 8);
        int n = wn + i * 16 + col;
        boff[i] = n * 32 + ((quad ^ sw(n)) * 8);
    }

    f32x4 acc[4][4] = {};
    for (int k0 = 0; k0 < DIM; k0 += 32) {
        __syncthreads();
        g2l16(ap0 + k0, lA0);
        g2l16(ap1 + k0, lA1);
        g2l16(bp0 + k0, lB0);
        g2l16(bp1 + k0, lB1);
        __syncthreads();
        bf16x8 a[4], b[4];
#pragma unroll
        for (int i = 0; i < 4; i++) a[i] = *(const bf16x8*)&As[aoff[i]];
#pragma unroll
        for (int i = 0; i < 4; i++) b[i] = *(const bf16x8*)&Bs[boff[i]];
#pragma unroll
        for (int mi = 0; mi < 4; mi++)
#pragma unroll
            for (int ni = 0; ni < 4; ni++)
                acc[mi][ni] = __builtin_amdgcn_mfma_f32_16x16x32_bf16(a[mi], b[ni], acc[mi][ni], 0, 0, 0);
    }

#pragma unroll
    for (int mi = 0; mi < 4; mi++)
#pragma unroll
        for (int i = 0; i < 4; i++) {
            int m = wm + mi * 16 + quad * 4 + i;
            if (m0 + m < cnt) {
                size_t hrow = (size_t)(base + m0 + m) * HID + n0;
#pragma unroll
                for (int ni = 0; ni < 4; ni++)
                    hbuf[hrow + wn + ni * 16 + col] = f2bf(gelu_exact(acc[mi][ni][i]));
            }
        }
}

// GEMM2: ybuf[slot] = h[slot] @ w2[e]^T   (gate applied in combine)
__global__ __launch_bounds__(256) void gemm2_kernel(
    const unsigned short* __restrict__ hbuf, const unsigned short* __restrict__ w2b,
    unsigned short* __restrict__ ybuf,
    const int4* __restrict__ tile_map, const int* __restrict__ ntiles)
{
    if ((int)blockIdx.x >= *ntiles) return;
    int4 tm = tile_map[blockIdx.x];
    int e = tm.x, m0 = tm.y, base = tm.z, cnt = tm.w;
    int n0 = blockIdx.y * 128;

    __shared__ unsigned short As[128 * 32];
    __shared__ unsigned short Bs[128 * 32];

    int tid = threadIdx.x;
    int lane = tid & 63, wave = tid >> 6;

    int r0 = tid >> 2, r1 = 64 + (tid >> 2), seg = tid & 3;
    int a0i = base + m0 + r0; if (m0 + r0 >= cnt) a0i = base;
    int a1i = base + m0 + r1; if (m0 + r1 >= cnt) a1i = base;
    const unsigned short* ap0 = hbuf + (size_t)a0i * HID + (seg ^ sw(r0)) * 8;
    const unsigned short* ap1 = hbuf + (size_t)a1i * HID + (seg ^ sw(r1)) * 8;
    const unsigned short* bp0 = w2b + ((size_t)e * DIM + n0 + r0) * HID + (seg ^ sw(r0)) * 8;
    const unsigned short* bp1 = w2b + ((size_t)e * DIM + n0 + r1) * HID + (seg ^ sw(r1)) * 8;
    unsigned short* lA0 = &As[(size_t)tid * 8];
    unsigned short* lA1 = &As[(size_t)(256 + tid) * 8];
    unsigned short* lB0 = &Bs[(size_t)tid * 8];
    unsigned short* lB1 = &Bs[(size_t)(256 + tid) * 8];

    int wm = (wave >> 1) * 64, wn = (wave & 1) * 64;
    int quad = lane >> 4, col = lane & 15;
    int aoff[4], boff[4];
#pragma unroll
    for (int i = 0; i < 4; i++) {
        int m = wm + i * 16 + col;
        aoff[i] = m * 32 + ((quad ^ sw(m)) * 8);
        int n = wn + i * 16 + col;
        boff[i] = n * 32 + ((quad ^ sw(n)) * 8);
    }

    f32x4 acc[4][4] = {};
    for (int k0 = 0; k0 < HID; k0 += 32) {
        __syncthreads();
        g2l16(ap0 + k0, lA0);
        g2l16(ap1 + k0, lA1);
        g2l16(bp0 + k0, lB0);
        g2l16(bp1 + k0, lB1);
        __syncthreads();
        bf16x8 a[4], b[4];
#pragma unroll
        for (int i = 0; i < 4; i++) a[i] = *(const bf16x8*)&As[aoff[i]];
#pragma unroll
        for (int i = 0; i < 4; i++) b[i] = *(const bf16x8*)&Bs[boff[i]];
#pragma unroll
        for (int mi = 0; mi < 4; mi++)
#pragma unroll
            for (int ni = 0; ni < 4; ni++)
                acc[mi][ni] = __builtin_amdgcn_mfma_f32_16x16x32_bf16(a[mi], b[ni], acc[mi][ni], 0, 0, 0);
    }

#pragma unroll
    for (int mi = 0; mi < 4; mi++)
#pragma unroll
        for (int i = 0; i < 4; i++) {
            int m = wm + mi * 16 + quad * 4 + i;
            if (m0 + m < cnt) {
                size_t yrow = (size_t)(base + m0 + m) * DIM + n0;
#pragma unroll
                for (int ni = 0; ni < 4; ni++)
                    ybuf[yrow + wn + ni * 16 + col] = f2bf(acc[mi][ni][i]);
            }
        }
}

// -------- combine: out = x + g0*y[slot0] + g1*y[slot1] --------
__global__ __launch_bounds__(256) void combine_kernel(
    const float* __restrict__ x, const unsigned short* __restrict__ ybuf,
    const int2* __restrict__ inv, const float2* __restrict__ gates,
    float* __restrict__ out)
{
    int tid = threadIdx.x;
    int wave = tid >> 6, lane = tid & 63;
    int t = blockIdx.x * 4 + wave;
    int2 sl = inv[t];
    float2 g = gates[t];
    const float* xr = x + (size_t)t * DIM;
    const unsigned short* y0 = ybuf + (size_t)sl.x * DIM;
    const unsigned short* y1 = ybuf + (size_t)sl.y * DIM;
    float* orow = out + (size_t)t * DIM;
#pragma unroll
    for (int j = 0; j < 4; j++) {
        int idx = j * 256 + lane * 4;
        float4 xv = *(const float4*)(xr + idx);
        ushort4 a = *(const ushort4*)(y0 + idx);
        ushort4 b = *(const ushort4*)(y1 + idx);
        float4 o;
        o.x = xv.x + g.x * bf2f(a.x) + g.y * bf2f(b.x);
        o.y = xv.y + g.x * bf2f(a.y) + g.y * bf2f(b.y);
        o.z = xv.z + g.x * bf2f(a.z) + g.y * bf2f(b.z);
        o.w = xv.w + g.x * bf2f(a.w) + g.y * bf2f(b.w);
        *(float4*)(orow + idx) = o;
    }
}

extern "C" void kernel_launch(void* const* d_in, const int* in_sizes, int n_in,
                              void* d_out, int out_size, void* d_ws, size_t ws_size,
                              hipStream_t stream) {
    (void)in_sizes; (void)n_in; (void)out_size; (void)ws_size;
    const float* x     = (const float*)d_in[0];
    const float* gw    = (const float*)d_in[1];
    const float* w1    = (const float*)d_in[2];
    const float* w2    = (const float*)d_in[3];
    const float* gamma = (const float*)d_in[4];
    const float* beta  = (const float*)d_in[5];
    float* out = (float*)d_out;
    char* ws = (char*)d_ws;

    unsigned short* xnb  = (unsigned short*)(ws + OFF_XN);
    unsigned short* w1b  = (unsigned short*)(ws + OFF_W1B);
    unsigned short* w2b  = (unsigned short*)(ws + OFF_W2B);
    unsigned short* hbuf = (unsigned short*)(ws + OFF_H);
    unsigned short* ybuf = (unsigned short*)(ws + OFF_W1B);  // reuse w1b after gemm1
    int*    atok    = (int*)(ws + OFF_ATOK);
    int2*   inv     = (int2*)(ws + OFF_INV);
    int*    topi    = (int*)(ws + OFF_TOPI);
    float2* gates   = (float2*)(ws + OFF_GATES);
    int*    cpart   = (int*)(ws + OFF_CPART);
    float*  ppart   = (float*)(ws + OFF_PPART);
    int*    counts  = (int*)(ws + OFF_COUNTS);
    int*    offsets = (int*)(ws + OFF_OFFS);
    int*    cnt2    = (int*)(ws + OFF_CNT2);
    int*    ntiles  = (int*)(ws + OFF_NT);
    int4*   tmap    = (int4*)(ws + OFF_TMAP);

    // zero the partial histograms (cpart+ppart contiguous 4 KB)
    hipMemsetAsync(ws + OFF_CPART, 0, 4096, stream);

    convert_kernel<<<16384, 256, 0, stream>>>((const float4*)w1, (ushort4*)w1b, (NE*HID*DIM)/4);
    convert_kernel<<<16384, 256, 0, stream>>>((const float4*)w2, (ushort4*)w2b, (NE*DIM*HID)/4);

    ln_router_kernel<<<T_TOK / 4, 256, 0, stream>>>(x, gw, gamma, beta, xnb, topi, gates, cpart, ppart);
    finalize_kernel<<<1, 64, 0, stream>>>(cpart, ppart, counts, offsets, cnt2, ntiles, tmap,
                                          out + (size_t)T_TOK * DIM);
    placement_kernel<<<T_TOK / 256, 256, 0, stream>>>(topi, offsets, cnt2, atok, inv);

    gemm1_kernel<<<dim3(136, HID / 128), 256, 0, stream>>>(xnb, w1b, hbuf, atok, tmap, ntiles);
    gemm2_kernel<<<dim3(136, DIM / 128), 256, 0, stream>>>(hbuf, w2b, ybuf, tmap, ntiles);
    combine_kernel<<<T_TOK / 4, 256, 0, stream>>>(x, ybuf, inv, gates, out);
}

// Round 3
// 448.469 us; speedup vs baseline: 1.3535x; 1.0404x over previous
//
#include <hip/hip_runtime.h>

#define T_TOK 8192
#define DIM 1024
#define HID 2048
#define NE 8
#define TK 16384   // T_TOK * 2

typedef __bf16 bf16x8 __attribute__((ext_vector_type(8)));
typedef float f32x4 __attribute__((ext_vector_type(4)));

// ---------------- ws layout (bytes) ----------------
#define OFF_XN      0UL            // T*D*2            = 16,777,216
#define OFF_W1B     16777216UL     // E*H*D*2          = 33,554,432  (reused as ybuf after gemm1)
#define OFF_W2B     50331648UL     // E*D*H*2          = 33,554,432
#define OFF_H       83886080UL     // TK*H*2           = 67,108,864
#define OFF_ATOK    150994944UL    // TK*4
#define OFF_INV     151060480UL    // T*8 (int2)
#define OFF_TOPI    151126016UL    // T*4
#define OFF_GATES   151158784UL    // T*8 (float2)
#define OFF_CPART   151224320UL    // 64*8*4
#define OFF_PPART   151226368UL    // 64*8*4
#define OFF_COUNTS  151228416UL    // 8*4
#define OFF_OFFS    151228448UL
#define OFF_CNT2    151228480UL
#define OFF_NT      151228512UL
#define OFF_TMAP    151228544UL    // 136*16

__device__ __forceinline__ unsigned short f2bf(float f) {
    union { float fv; unsigned u; } q; q.fv = f;
    unsigned r = q.u + 0x7fffu + ((q.u >> 16) & 1u);
    return (unsigned short)(r >> 16);
}

__device__ __forceinline__ float bf2f(unsigned short u) {
    union { unsigned u; float f; } q; q.u = ((unsigned)u) << 16;
    return q.f;
}

// tanh-form GELU on hw exp/rcp: ~9 VALU vs ~25 for erff. |err| < 1e-3 abs,
// well under bf16 h-storage rounding. Saturates correctly at +/-inf.
__device__ __forceinline__ float gelu_fast(float x) {
    float x3 = x * x * x;
    float z2 = 1.5957691216f * (x + 0.044715f * x3);   // 2 * sqrt(2/pi) * (...)
    float u = __expf(z2);
    float t = 1.0f - 2.0f * __builtin_amdgcn_rcpf(u + 1.0f);
    return 0.5f * x * (1.0f + t);
}

// 8-segment XOR swizzle (BK=64 rows are 8 x 16B segs): reader lands 2-way on
// bank groups (free, m136).
__device__ __forceinline__ int sw8(int r) { return (r ^ (r >> 3)) & 7; }

// async 16B global -> LDS; lds ptr must be wave-uniform base + lane*16.
__device__ __forceinline__ void g2l16(const unsigned short* g, unsigned short* l) {
    __builtin_amdgcn_global_load_lds(
        (const __attribute__((address_space(1))) unsigned int*)g,
        (__attribute__((address_space(3))) unsigned int*)l, 16, 0, 0);
}

// -------- fp32 -> bf16 conversion (both weight tensors, one launch) --------
__global__ __launch_bounds__(256) void convert_kernel(
    const float4* __restrict__ s1, ushort4* __restrict__ d1, int n1,
    const float4* __restrict__ s2, ushort4* __restrict__ d2, int n2)
{
    int i = blockIdx.x * 256 + threadIdx.x;
    if (i < n1) {
        float4 f = s1[i];
        ushort4 u; u.x = f2bf(f.x); u.y = f2bf(f.y); u.z = f2bf(f.z); u.w = f2bf(f.w);
        d1[i] = u;
    } else {
        int j = i - n1;
        if (j < n2) {
            float4 f = s2[j];
            ushort4 u; u.x = f2bf(f.x); u.y = f2bf(f.y); u.z = f2bf(f.z); u.w = f2bf(f.w);
            d2[j] = u;
        }
    }
}

// -------- fused LayerNorm + router --------
__global__ __launch_bounds__(256) void ln_router_kernel(
    const float* __restrict__ x, const float* __restrict__ gw,
    const float* __restrict__ gamma, const float* __restrict__ beta,
    unsigned short* __restrict__ xnb, int* __restrict__ top_idx,
    float2* __restrict__ gates, int* __restrict__ counts_partial,
    float* __restrict__ probs_partial)
{
    __shared__ float sprob[8];
    __shared__ int scnt[8];
    int tid = threadIdx.x;
    if (tid < 8) { sprob[tid] = 0.f; scnt[tid] = 0; }
    __syncthreads();

    int wave = tid >> 6, lane = tid & 63;
    int t = blockIdx.x * 4 + wave;
    const float* xt = x + (size_t)t * DIM;

    float v[16];
    float s = 0.f, sq = 0.f;
#pragma unroll
    for (int j = 0; j < 4; j++) {
        float4 f = *(const float4*)(xt + j * 256 + lane * 4);
        v[4*j+0] = f.x; v[4*j+1] = f.y; v[4*j+2] = f.z; v[4*j+3] = f.w;
        s += f.x + f.y + f.z + f.w;
        sq += f.x*f.x + f.y*f.y + f.z*f.z + f.w*f.w;
    }
#pragma unroll
    for (int o = 32; o > 0; o >>= 1) { s += __shfl_xor(s, o); sq += __shfl_xor(sq, o); }
    float mean = s * (1.0f / DIM);
    float var = sq * (1.0f / DIM) - mean * mean;
    float rstd = rsqrtf(var + 1e-5f);

#pragma unroll
    for (int j = 0; j < 4; j++) {
        float4 gm = *(const float4*)(gamma + j * 256 + lane * 4);
        float4 bt = *(const float4*)(beta + j * 256 + lane * 4);
        float x0 = (v[4*j+0] - mean) * rstd * gm.x + bt.x;
        float x1 = (v[4*j+1] - mean) * rstd * gm.y + bt.y;
        float x2 = (v[4*j+2] - mean) * rstd * gm.z + bt.z;
        float x3 = (v[4*j+3] - mean) * rstd * gm.w + bt.w;
        ushort4 u; u.x = f2bf(x0); u.y = f2bf(x1); u.z = f2bf(x2); u.w = f2bf(x3);
        *(ushort4*)(xnb + (size_t)t * DIM + j * 256 + lane * 4) = u;
        v[4*j+0] = x0; v[4*j+1] = x1; v[4*j+2] = x2; v[4*j+3] = x3;
    }

    // router logits in fp64 (top-k stability vs reference)
    double part[8];
#pragma unroll
    for (int e = 0; e < 8; e++) {
        double p = 0.0;
        const float* ge = gw + (size_t)e * DIM;
#pragma unroll
        for (int j = 0; j < 4; j++) {
            float4 g = *(const float4*)(ge + j * 256 + lane * 4);
            p += (double)v[4*j+0] * (double)g.x;
            p += (double)v[4*j+1] * (double)g.y;
            p += (double)v[4*j+2] * (double)g.z;
            p += (double)v[4*j+3] * (double)g.w;
        }
        part[e] = p;
    }
#pragma unroll
    for (int o = 32; o > 0; o >>= 1)
#pragma unroll
        for (int e = 0; e < 8; e++) part[e] += __shfl_xor(part[e], o);

    if (lane == 0) {
        double l0 = -1e300; int e0 = -1;
#pragma unroll
        for (int e = 0; e < 8; e++) if (part[e] > l0) { l0 = part[e]; e0 = e; }
        double l1 = -1e300; int e1 = -1;
#pragma unroll
        for (int e = 0; e < 8; e++) if (e != e0 && part[e] > l1) { l1 = part[e]; e1 = e; }
        float d = expf((float)(l1 - l0));
        float g0 = 1.0f / (1.0f + d);
        float g1 = d / (1.0f + d);
        top_idx[t] = e0 | (e1 << 8);
        gates[t] = make_float2(g0, g1);
        atomicAdd(&scnt[e0], 1);
        atomicAdd(&scnt[e1], 1);
        float pe[8]; float sum = 0.f;
#pragma unroll
        for (int e = 0; e < 8; e++) { pe[e] = expf((float)(part[e] - l0)); sum += pe[e]; }
        float inv = 1.0f / sum;
#pragma unroll
        for (int e = 0; e < 8; e++) atomicAdd(&sprob[e], pe[e] * inv);
    }
    __syncthreads();
    if (tid < 8) {
        int bin = (blockIdx.x & 63) * 8 + tid;
        atomicAdd(&probs_partial[bin], sprob[tid]);
        atomicAdd(&counts_partial[bin], scnt[tid]);
    }
}

// -------- finalize (64-thread parallel reduce): counts, offsets, tiles, lb --------
__global__ void finalize_kernel(const int* __restrict__ counts_partial,
                                const float* __restrict__ probs_partial,
                                int* __restrict__ counts, int* __restrict__ offsets,
                                int* __restrict__ cnt2, int* __restrict__ ntiles,
                                int4* __restrict__ tile_map, float* __restrict__ lb_out)
{
    int tid = threadIdx.x;  // 64 threads: thread t loads bin row t
    int c[8]; float p[8];
#pragma unroll
    for (int e = 0; e < 8; e++) { c[e] = counts_partial[tid*8+e]; p[e] = probs_partial[tid*8+e]; }
#pragma unroll
    for (int o = 32; o > 0; o >>= 1)
#pragma unroll
        for (int e = 0; e < 8; e++) { c[e] += __shfl_xor(c[e], o); p[e] += __shfl_xor(p[e], o); }

    if (tid == 0) {
        int off = 0, nt = 0;
        for (int e = 0; e < 8; e++) {
            offsets[e] = off; counts[e] = c[e]; cnt2[e] = 0;
            for (int m0 = 0; m0 < c[e]; m0 += 128) tile_map[nt++] = make_int4(e, m0, off, c[e]);
            off += c[e];
        }
        *ntiles = nt;
        float avg[8]; float m = 0.f;
        for (int e = 0; e < 8; e++) { avg[e] = p[e] / (float)T_TOK; m += avg[e]; }
        m *= (1.0f / 8.0f);
        float var = 0.f;
        for (int e = 0; e < 8; e++) { float d = avg[e] - m; var += d * d; }
        var *= (1.0f / 7.0f);
        float mm = m + 1e-6f;
        lb_out[0] = (var / (mm * mm)) * 0.01f;
    }
}

// -------- placement: per-expert token lists + inverse slot map --------
__global__ __launch_bounds__(256) void placement_kernel(
    const int* __restrict__ top_idx,
    const int* __restrict__ offsets, int* __restrict__ cnt2,
    int* __restrict__ atok, int2* __restrict__ inv)
{
    __shared__ int lcnt[8];
    __shared__ int lbase[8];
    __shared__ int ltok[4096];
    int tid = threadIdx.x;
    if (tid < 8) lcnt[tid] = 0;
    __syncthreads();
    int t = blockIdx.x * 256 + tid;
    int pk = top_idx[t];
    int e0 = pk & 255, e1 = (pk >> 8) & 255;
    int p0 = atomicAdd(&lcnt[e0], 1); ltok[e0*512+p0] = t;
    int p1 = atomicAdd(&lcnt[e1], 1); ltok[e1*512+p1] = t;
    __syncthreads();
    if (tid < 8) lbase[tid] = offsets[tid] + atomicAdd(&cnt2[tid], lcnt[tid]);
    __syncthreads();
    for (int e = 0; e < 8; e++) {
        int c = lcnt[e], b = lbase[e];
        for (int i = tid; i < c; i += 256) atok[b+i] = ltok[e*512+i];
    }
    inv[t] = make_int2(lbase[e0] + p0, lbase[e1] + p1);
}

// ======== grouped GEMM: 128x128 tile, BK=64, global_load_lds width=16 ========
// GEMM1: h[slot] = gelu(xn[atok[slot]] @ w1[e]^T)
__global__ __launch_bounds__(256) void gemm1_kernel(
    const unsigned short* __restrict__ xnb, const unsigned short* __restrict__ w1b,
    unsigned short* __restrict__ hbuf, const int* __restrict__ atok,
    const int4* __restrict__ tile_map, const int* __restrict__ ntiles)
{
    if ((int)blockIdx.x >= *ntiles) return;
    int4 tm = tile_map[blockIdx.x];
    int e = tm.x, m0 = tm.y, base = tm.z, cnt = tm.w;
    int n0 = blockIdx.y * 128;

    __shared__ unsigned short As[128 * 64];
    __shared__ unsigned short Bs[128 * 64];

    int tid = threadIdx.x, lane = tid & 63, wave = tid >> 6;
    int sg = tid & 7;

    const unsigned short* ap[4];
    const unsigned short* bp[4];
#pragma unroll
    for (int j = 0; j < 4; j++) {
        int r = j * 32 + (tid >> 3);
        int ai = base + m0 + r; if (m0 + r >= cnt) ai = base;
        int tok = atok[ai];
        int ss = (sg ^ sw8(r)) * 8;
        ap[j] = xnb + (size_t)tok * DIM + ss;
        bp[j] = w1b + ((size_t)e * HID + n0 + r) * DIM + ss;
    }

    int wm = (wave >> 1) * 64, wn = (wave & 1) * 64;
    int quad = lane >> 4, col = lane & 15;
    int aoff[4][2], boff[4][2];
#pragma unroll
    for (int i = 0; i < 4; i++)
#pragma unroll
        for (int s = 0; s < 2; s++) {
            int m = wm + i * 16 + col;
            aoff[i][s] = m * 64 + ((((s << 2) | quad) ^ sw8(m)) * 8);
            int n = wn + i * 16 + col;
            boff[i][s] = n * 64 + ((((s << 2) | quad) ^ sw8(n)) * 8);
        }

    f32x4 acc[4][4] = {};
    for (int k0 = 0; k0 < DIM; k0 += 64) {
        __syncthreads();
#pragma unroll
        for (int j = 0; j < 4; j++) {
            g2l16(ap[j] + k0, &As[(j * 256 + tid) * 8]);
            g2l16(bp[j] + k0, &Bs[(j * 256 + tid) * 8]);
        }
        __syncthreads();
#pragma unroll
        for (int s = 0; s < 2; s++) {
            bf16x8 a[4], b[4];
#pragma unroll
            for (int i = 0; i < 4; i++) a[i] = *(const bf16x8*)&As[aoff[i][s]];
#pragma unroll
            for (int i = 0; i < 4; i++) b[i] = *(const bf16x8*)&Bs[boff[i][s]];
#pragma unroll
            for (int mi = 0; mi < 4; mi++)
#pragma unroll
                for (int ni = 0; ni < 4; ni++)
                    acc[mi][ni] = __builtin_amdgcn_mfma_f32_16x16x32_bf16(a[mi], b[ni], acc[mi][ni], 0, 0, 0);
        }
    }

#pragma unroll
    for (int mi = 0; mi < 4; mi++)
#pragma unroll
        for (int i = 0; i < 4; i++) {
            int m = wm + mi * 16 + quad * 4 + i;
            if (m0 + m < cnt) {
                size_t hrow = (size_t)(base + m0 + m) * HID + n0;
#pragma unroll
                for (int ni = 0; ni < 4; ni++)
                    hbuf[hrow + wn + ni * 16 + col] = f2bf(gelu_fast(acc[mi][ni][i]));
            }
        }
}

// GEMM2: ybuf[slot] = h[slot] @ w2[e]^T   (gate applied in combine)
__global__ __launch_bounds__(256) void gemm2_kernel(
    const unsigned short* __restrict__ hbuf, const unsigned short* __restrict__ w2b,
    unsigned short* __restrict__ ybuf,
    const int4* __restrict__ tile_map, const int* __restrict__ ntiles)
{
    if ((int)blockIdx.x >= *ntiles) return;
    int4 tm = tile_map[blockIdx.x];
    int e = tm.x, m0 = tm.y, base = tm.z, cnt = tm.w;
    int n0 = blockIdx.y * 128;

    __shared__ unsigned short As[128 * 64];
    __shared__ unsigned short Bs[128 * 64];

    int tid = threadIdx.x, lane = tid & 63, wave = tid >> 6;
    int sg = tid & 7;

    const unsigned short* ap[4];
    const unsigned short* bp[4];
#pragma unroll
    for (int j = 0; j < 4; j++) {
        int r = j * 32 + (tid >> 3);
        int ai = base + m0 + r; if (m0 + r >= cnt) ai = base;
        int ss = (sg ^ sw8(r)) * 8;
        ap[j] = hbuf + (size_t)ai * HID + ss;
        bp[j] = w2b + ((size_t)e * DIM + n0 + r) * HID + ss;
    }

    int wm = (wave >> 1) * 64, wn = (wave & 1) * 64;
    int quad = lane >> 4, col = lane & 15;
    int aoff[4][2], boff[4][2];
#pragma unroll
    for (int i = 0; i < 4; i++)
#pragma unroll
        for (int s = 0; s < 2; s++) {
            int m = wm + i * 16 + col;
            aoff[i][s] = m * 64 + ((((s << 2) | quad) ^ sw8(m)) * 8);
            int n = wn + i * 16 + col;
            boff[i][s] = n * 64 + ((((s << 2) | quad) ^ sw8(n)) * 8);
        }

    f32x4 acc[4][4] = {};
    for (int k0 = 0; k0 < HID; k0 += 64) {
        __syncthreads();
#pragma unroll
        for (int j = 0; j < 4; j++) {
            g2l16(ap[j] + k0, &As[(j * 256 + tid) * 8]);
            g2l16(bp[j] + k0, &Bs[(j * 256 + tid) * 8]);
        }
        __syncthreads();
#pragma unroll
        for (int s = 0; s < 2; s++) {
            bf16x8 a[4], b[4];
#pragma unroll
            for (int i = 0; i < 4; i++) a[i] = *(const bf16x8*)&As[aoff[i][s]];
#pragma unroll
            for (int i = 0; i < 4; i++) b[i] = *(const bf16x8*)&Bs[boff[i][s]];
#pragma unroll
            for (int mi = 0; mi < 4; mi++)
#pragma unroll
                for (int ni = 0; ni < 4; ni++)
                    acc[mi][ni] = __builtin_amdgcn_mfma_f32_16x16x32_bf16(a[mi], b[ni], acc[mi][ni], 0, 0, 0);
        }
    }

#pragma unroll
    for (int mi = 0; mi < 4; mi++)
#pragma unroll
        for (int i = 0; i < 4; i++) {
            int m = wm + mi * 16 + quad * 4 + i;
            if (m0 + m < cnt) {
                size_t yrow = (size_t)(base + m0 + m) * DIM + n0;
#pragma unroll
                for (int ni = 0; ni < 4; ni++)
                    ybuf[yrow + wn + ni * 16 + col] = f2bf(acc[mi][ni][i]);
            }
        }
}

// -------- combine: out = x + g0*y[slot0] + g1*y[slot1] --------
__global__ __launch_bounds__(256) void combine_kernel(
    const float* __restrict__ x, const unsigned short* __restrict__ ybuf,
    const int2* __restrict__ inv, const float2* __restrict__ gates,
    float* __restrict__ out)
{
    int tid = threadIdx.x;
    int wave = tid >> 6, lane = tid & 63;
    int t = blockIdx.x * 4 + wave;
    int2 sl = inv[t];
    float2 g = gates[t];
    const float* xr = x + (size_t)t * DIM;
    const unsigned short* y0 = ybuf + (size_t)sl.x * DIM;
    const unsigned short* y1 = ybuf + (size_t)sl.y * DIM;
    float* orow = out + (size_t)t * DIM;
#pragma unroll
    for (int j = 0; j < 4; j++) {
        int idx = j * 256 + lane * 4;
        float4 xv = *(const float4*)(xr + idx);
        ushort4 a = *(const ushort4*)(y0 + idx);
        ushort4 b = *(const ushort4*)(y1 + idx);
        float4 o;
        o.x = xv.x + g.x * bf2f(a.x) + g.y * bf2f(b.x);
        o.y = xv.y + g.x * bf2f(a.y) + g.y * bf2f(b.y);
        o.z = xv.z + g.x * bf2f(a.z) + g.y * bf2f(b.z);
        o.w = xv.w + g.x * bf2f(a.w) + g.y * bf2f(b.w);
        *(float4*)(orow + idx) = o;
    }
}

extern "C" void kernel_launch(void* const* d_in, const int* in_sizes, int n_in,
                              void* d_out, int out_size, void* d_ws, size_t ws_size,
                              hipStream_t stream) {
    (void)in_sizes; (void)n_in; (void)out_size; (void)ws_size;
    const float* x     = (const float*)d_in[0];
    const float* gw    = (const float*)d_in[1];
    const float* w1    = (const float*)d_in[2];
    const float* w2    = (const float*)d_in[3];
    const float* gamma = (const float*)d_in[4];
    const float* beta  = (const float*)d_in[5];
    float* out = (float*)d_out;
    char* ws = (char*)d_ws;

    unsigned short* xnb  = (unsigned short*)(ws + OFF_XN);
    unsigned short* w1b  = (unsigned short*)(ws + OFF_W1B);
    unsigned short* w2b  = (unsigned short*)(ws + OFF_W2B);
    unsigned short* hbuf = (unsigned short*)(ws + OFF_H);
    unsigned short* ybuf = (unsigned short*)(ws + OFF_W1B);  // reuse w1b after gemm1
    int*    atok    = (int*)(ws + OFF_ATOK);
    int2*   inv     = (int2*)(ws + OFF_INV);
    int*    topi    = (int*)(ws + OFF_TOPI);
    float2* gates   = (float2*)(ws + OFF_GATES);
    int*    cpart   = (int*)(ws + OFF_CPART);
    float*  ppart   = (float*)(ws + OFF_PPART);
    int*    counts  = (int*)(ws + OFF_COUNTS);
    int*    offsets = (int*)(ws + OFF_OFFS);
    int*    cnt2    = (int*)(ws + OFF_CNT2);
    int*    ntiles  = (int*)(ws + OFF_NT);
    int4*   tmap    = (int4*)(ws + OFF_TMAP);

    // zero the partial histograms (cpart+ppart contiguous 4 KB)
    hipMemsetAsync(ws + OFF_CPART, 0, 4096, stream);

    int n1 = (NE * HID * DIM) / 4, n2 = (NE * DIM * HID) / 4;
    convert_kernel<<<(n1 + n2 + 255) / 256, 256, 0, stream>>>(
        (const float4*)w1, (ushort4*)w1b, n1, (const float4*)w2, (ushort4*)w2b, n2);

    ln_router_kernel<<<T_TOK / 4, 256, 0, stream>>>(x, gw, gamma, beta, xnb, topi, gates, cpart, ppart);
    finalize_kernel<<<1, 64, 0, stream>>>(cpart, ppart, counts, offsets, cnt2, ntiles, tmap,
                                          out + (size_t)T_TOK * DIM);
    placement_kernel<<<T_TOK / 256, 256, 0, stream>>>(topi, offsets, cnt2, atok, inv);

    gemm1_kernel<<<dim3(136, HID / 128), 256, 0, stream>>>(xnb, w1b, hbuf, atok, tmap, ntiles);
    gemm2_kernel<<<dim3(136, DIM / 128), 256, 0, stream>>>(hbuf, w2b, ybuf, tmap, ntiles);
    combine_kernel<<<T_TOK / 4, 256, 0, stream>>>(x, ybuf, inv, gates, out);
}

// Round 4
// 434.855 us; speedup vs baseline: 1.3959x; 1.0313x over previous
//
#include <hip/hip_runtime.h>

#define T_TOK 8192
#define DIM 1024
#define HID 2048
#define NE 8
#define TK 16384   // T_TOK * 2

typedef __bf16 bf16x8 __attribute__((ext_vector_type(8)));
typedef float f32x16 __attribute__((ext_vector_type(16)));

// ---------------- ws layout (bytes) ----------------
#define OFF_XN      0UL            // T*D*2            = 16,777,216
#define OFF_W1B     16777216UL     // E*H*D*2          = 33,554,432  (reused as ybuf after gemm1)
#define OFF_W2B     50331648UL     // E*D*H*2          = 33,554,432
#define OFF_H       83886080UL     // TK*H*2           = 67,108,864
#define OFF_ATOK    150994944UL    // TK*4
#define OFF_INV     151060480UL    // T*8 (int2)
#define OFF_TOPI    151126016UL    // T*4
#define OFF_GATES   151158784UL    // T*8 (float2)
#define OFF_CPART   151224320UL    // 64*8*4
#define OFF_PPART   151226368UL    // 64*8*4
#define OFF_COUNTS  151228416UL    // 8*4
#define OFF_OFFS    151228448UL
#define OFF_CNT2    151228480UL
#define OFF_NT      151228512UL
#define OFF_TMAP    151228544UL    // 136*16

__device__ __forceinline__ unsigned short f2bf(float f) {
    union { float fv; unsigned u; } q; q.fv = f;
    unsigned r = q.u + 0x7fffu + ((q.u >> 16) & 1u);
    return (unsigned short)(r >> 16);
}

__device__ __forceinline__ float bf2f(unsigned short u) {
    union { unsigned u; float f; } q; q.u = ((unsigned)u) << 16;
    return q.f;
}

// tanh-form GELU on hw exp/rcp: ~9 VALU vs ~25 for erff. |err| < 1e-3 abs,
// well under bf16 h-storage rounding.
__device__ __forceinline__ float gelu_fast(float x) {
    float x3 = x * x * x;
    float z2 = 1.5957691216f * (x + 0.044715f * x3);   // 2 * sqrt(2/pi) * (...)
    float u = __expf(z2);
    float t = 1.0f - 2.0f * __builtin_amdgcn_rcpf(u + 1.0f);
    return 0.5f * x * (1.0f + t);
}

// 8-segment XOR swizzle (BK=64 rows are 8 x 16B segs).
__device__ __forceinline__ int sw8(int r) { return (r ^ (r >> 3)) & 7; }

// async 16B global -> LDS; lds ptr must be wave-uniform base + lane*16.
__device__ __forceinline__ void g2l16(const unsigned short* g, unsigned short* l) {
    __builtin_amdgcn_global_load_lds(
        (const __attribute__((address_space(1))) unsigned int*)g,
        (__attribute__((address_space(3))) unsigned int*)l, 16, 0, 0);
}

// -------- fp32 -> bf16 conversion (both weight tensors, one launch) --------
__global__ __launch_bounds__(256) void convert_kernel(
    const float4* __restrict__ s1, ushort4* __restrict__ d1, int n1,
    const float4* __restrict__ s2, ushort4* __restrict__ d2, int n2)
{
    int i = blockIdx.x * 256 + threadIdx.x;
    if (i < n1) {
        float4 f = s1[i];
        ushort4 u; u.x = f2bf(f.x); u.y = f2bf(f.y); u.z = f2bf(f.z); u.w = f2bf(f.w);
        d1[i] = u;
    } else {
        int j = i - n1;
        if (j < n2) {
            float4 f = s2[j];
            ushort4 u; u.x = f2bf(f.x); u.y = f2bf(f.y); u.z = f2bf(f.z); u.w = f2bf(f.w);
            d2[j] = u;
        }
    }
}

// -------- fused LayerNorm + router --------
__global__ __launch_bounds__(256) void ln_router_kernel(
    const float* __restrict__ x, const float* __restrict__ gw,
    const float* __restrict__ gamma, const float* __restrict__ beta,
    unsigned short* __restrict__ xnb, int* __restrict__ top_idx,
    float2* __restrict__ gates, int* __restrict__ counts_partial,
    float* __restrict__ probs_partial)
{
    __shared__ float sprob[8];
    __shared__ int scnt[8];
    int tid = threadIdx.x;
    if (tid < 8) { sprob[tid] = 0.f; scnt[tid] = 0; }
    __syncthreads();

    int wave = tid >> 6, lane = tid & 63;
    int t = blockIdx.x * 4 + wave;
    const float* xt = x + (size_t)t * DIM;

    float v[16];
    float s = 0.f, sq = 0.f;
#pragma unroll
    for (int j = 0; j < 4; j++) {
        float4 f = *(const float4*)(xt + j * 256 + lane * 4);
        v[4*j+0] = f.x; v[4*j+1] = f.y; v[4*j+2] = f.z; v[4*j+3] = f.w;
        s += f.x + f.y + f.z + f.w;
        sq += f.x*f.x + f.y*f.y + f.z*f.z + f.w*f.w;
    }
#pragma unroll
    for (int o = 32; o > 0; o >>= 1) { s += __shfl_xor(s, o); sq += __shfl_xor(sq, o); }
    float mean = s * (1.0f / DIM);
    float var = sq * (1.0f / DIM) - mean * mean;
    float rstd = rsqrtf(var + 1e-5f);

#pragma unroll
    for (int j = 0; j < 4; j++) {
        float4 gm = *(const float4*)(gamma + j * 256 + lane * 4);
        float4 bt = *(const float4*)(beta + j * 256 + lane * 4);
        float x0 = (v[4*j+0] - mean) * rstd * gm.x + bt.x;
        float x1 = (v[4*j+1] - mean) * rstd * gm.y + bt.y;
        float x2 = (v[4*j+2] - mean) * rstd * gm.z + bt.z;
        float x3 = (v[4*j+3] - mean) * rstd * gm.w + bt.w;
        ushort4 u; u.x = f2bf(x0); u.y = f2bf(x1); u.z = f2bf(x2); u.w = f2bf(x3);
        *(ushort4*)(xnb + (size_t)t * DIM + j * 256 + lane * 4) = u;
        v[4*j+0] = x0; v[4*j+1] = x1; v[4*j+2] = x2; v[4*j+3] = x3;
    }

    // router logits in fp64 (top-k stability vs reference)
    double part[8];
#pragma unroll
    for (int e = 0; e < 8; e++) {
        double p = 0.0;
        const float* ge = gw + (size_t)e * DIM;
#pragma unroll
        for (int j = 0; j < 4; j++) {
            float4 g = *(const float4*)(ge + j * 256 + lane * 4);
            p += (double)v[4*j+0] * (double)g.x;
            p += (double)v[4*j+1] * (double)g.y;
            p += (double)v[4*j+2] * (double)g.z;
            p += (double)v[4*j+3] * (double)g.w;
        }
        part[e] = p;
    }
#pragma unroll
    for (int o = 32; o > 0; o >>= 1)
#pragma unroll
        for (int e = 0; e < 8; e++) part[e] += __shfl_xor(part[e], o);

    if (lane == 0) {
        double l0 = -1e300; int e0 = -1;
#pragma unroll
        for (int e = 0; e < 8; e++) if (part[e] > l0) { l0 = part[e]; e0 = e; }
        double l1 = -1e300; int e1 = -1;
#pragma unroll
        for (int e = 0; e < 8; e++) if (e != e0 && part[e] > l1) { l1 = part[e]; e1 = e; }
        float d = expf((float)(l1 - l0));
        float g0 = 1.0f / (1.0f + d);
        float g1 = d / (1.0f + d);
        top_idx[t] = e0 | (e1 << 8);
        gates[t] = make_float2(g0, g1);
        atomicAdd(&scnt[e0], 1);
        atomicAdd(&scnt[e1], 1);
        float pe[8]; float sum = 0.f;
#pragma unroll
        for (int e = 0; e < 8; e++) { pe[e] = expf((float)(part[e] - l0)); sum += pe[e]; }
        float inv = 1.0f / sum;
#pragma unroll
        for (int e = 0; e < 8; e++) atomicAdd(&sprob[e], pe[e] * inv);
    }
    __syncthreads();
    if (tid < 8) {
        int bin = (blockIdx.x & 63) * 8 + tid;
        atomicAdd(&probs_partial[bin], sprob[tid]);
        atomicAdd(&counts_partial[bin], scnt[tid]);
    }
}

// -------- finalize (64-thread parallel reduce): counts, offsets, tiles, lb --------
__global__ void finalize_kernel(const int* __restrict__ counts_partial,
                                const float* __restrict__ probs_partial,
                                int* __restrict__ counts, int* __restrict__ offsets,
                                int* __restrict__ cnt2, int* __restrict__ ntiles,
                                int4* __restrict__ tile_map, float* __restrict__ lb_out)
{
    int tid = threadIdx.x;  // 64 threads: thread t loads bin row t
    int c[8]; float p[8];
#pragma unroll
    for (int e = 0; e < 8; e++) { c[e] = counts_partial[tid*8+e]; p[e] = probs_partial[tid*8+e]; }
#pragma unroll
    for (int o = 32; o > 0; o >>= 1)
#pragma unroll
        for (int e = 0; e < 8; e++) { c[e] += __shfl_xor(c[e], o); p[e] += __shfl_xor(p[e], o); }

    if (tid == 0) {
        int off = 0, nt = 0;
        for (int e = 0; e < 8; e++) {
            offsets[e] = off; counts[e] = c[e]; cnt2[e] = 0;
            for (int m0 = 0; m0 < c[e]; m0 += 128) tile_map[nt++] = make_int4(e, m0, off, c[e]);
            off += c[e];
        }
        *ntiles = nt;
        float avg[8]; float m = 0.f;
        for (int e = 0; e < 8; e++) { avg[e] = p[e] / (float)T_TOK; m += avg[e]; }
        m *= (1.0f / 8.0f);
        float var = 0.f;
        for (int e = 0; e < 8; e++) { float d = avg[e] - m; var += d * d; }
        var *= (1.0f / 7.0f);
        float mm = m + 1e-6f;
        lb_out[0] = (var / (mm * mm)) * 0.01f;
    }
}

// -------- placement: per-expert token lists + inverse slot map --------
__global__ __launch_bounds__(256) void placement_kernel(
    const int* __restrict__ top_idx,
    const int* __restrict__ offsets, int* __restrict__ cnt2,
    int* __restrict__ atok, int2* __restrict__ inv)
{
    __shared__ int lcnt[8];
    __shared__ int lbase[8];
    __shared__ int ltok[4096];
    int tid = threadIdx.x;
    if (tid < 8) lcnt[tid] = 0;
    __syncthreads();
    int t = blockIdx.x * 256 + tid;
    int pk = top_idx[t];
    int e0 = pk & 255, e1 = (pk >> 8) & 255;
    int p0 = atomicAdd(&lcnt[e0], 1); ltok[e0*512+p0] = t;
    int p1 = atomicAdd(&lcnt[e1], 1); ltok[e1*512+p1] = t;
    __syncthreads();
    if (tid < 8) lbase[tid] = offsets[tid] + atomicAdd(&cnt2[tid], lcnt[tid]);
    __syncthreads();
    for (int e = 0; e < 8; e++) {
        int c = lcnt[e], b = lbase[e];
        for (int i = tid; i < c; i += 256) atok[b+i] = ltok[e*512+i];
    }
    inv[t] = make_int2(lbase[e0] + p0, lbase[e1] + p1);
}

// ======== grouped GEMM: 128x128 tile, BK=64, 32x32x16 MFMA, global_load_lds ========
// Fragment layout (m74/m101): A/B row(col)=lane&31, k=(lane>>5)*8+j.
// C/D: col=lane&31, row=(reg&3)+8*(reg>>2)+4*(lane>>5).
// GEMM1: h[slot] = gelu(xn[atok[slot]] @ w1[e]^T)
__global__ __launch_bounds__(256) void gemm1_kernel(
    const unsigned short* __restrict__ xnb, const unsigned short* __restrict__ w1b,
    unsigned short* __restrict__ hbuf, const int* __restrict__ atok,
    const int4* __restrict__ tile_map, const int* __restrict__ ntiles)
{
    if ((int)blockIdx.x >= *ntiles) return;
    int4 tm = tile_map[blockIdx.x];
    int e = tm.x, m0 = tm.y, base = tm.z, cnt = tm.w;
    int n0 = blockIdx.y * 128;

    __shared__ unsigned short As[128 * 64];
    __shared__ unsigned short Bs[128 * 64];

    int tid = threadIdx.x, lane = tid & 63, wave = tid >> 6;
    int sg = tid & 7;

    const unsigned short* ap[4];
    const unsigned short* bp[4];
#pragma unroll
    for (int j = 0; j < 4; j++) {
        int r = j * 32 + (tid >> 3);
        int ai = base + m0 + r; if (m0 + r >= cnt) ai = base;
        int tok = atok[ai];
        int ss = (sg ^ sw8(r)) * 8;
        ap[j] = xnb + (size_t)tok * DIM + ss;
        bp[j] = w1b + ((size_t)e * HID + n0 + r) * DIM + ss;
    }

    int wm = (wave >> 1) * 64, wn = (wave & 1) * 64;
    int r32 = lane & 31, hl = lane >> 5;
    int aoff[2][4], boff[2][4];
#pragma unroll
    for (int mi = 0; mi < 2; mi++)
#pragma unroll
        for (int s = 0; s < 4; s++) {
            int m = wm + mi * 32 + r32;
            int seg = s * 2 + hl;
            aoff[mi][s] = m * 64 + ((seg ^ sw8(m)) * 8);
            int n = wn + mi * 32 + r32;
            boff[mi][s] = n * 64 + ((seg ^ sw8(n)) * 8);
        }

    f32x16 acc[2][2] = {};
    for (int k0 = 0; k0 < DIM; k0 += 64) {
        __syncthreads();
#pragma unroll
        for (int j = 0; j < 4; j++) {
            g2l16(ap[j] + k0, &As[(j * 256 + tid) * 8]);
            g2l16(bp[j] + k0, &Bs[(j * 256 + tid) * 8]);
        }
        __syncthreads();
#pragma unroll
        for (int s = 0; s < 4; s++) {
            bf16x8 a0 = *(const bf16x8*)&As[aoff[0][s]];
            bf16x8 a1 = *(const bf16x8*)&As[aoff[1][s]];
            bf16x8 b0 = *(const bf16x8*)&Bs[boff[0][s]];
            bf16x8 b1 = *(const bf16x8*)&Bs[boff[1][s]];
            acc[0][0] = __builtin_amdgcn_mfma_f32_32x32x16_bf16(a0, b0, acc[0][0], 0, 0, 0);
            acc[0][1] = __builtin_amdgcn_mfma_f32_32x32x16_bf16(a0, b1, acc[0][1], 0, 0, 0);
            acc[1][0] = __builtin_amdgcn_mfma_f32_32x32x16_bf16(a1, b0, acc[1][0], 0, 0, 0);
            acc[1][1] = __builtin_amdgcn_mfma_f32_32x32x16_bf16(a1, b1, acc[1][1], 0, 0, 0);
        }
    }

#pragma unroll
    for (int mi = 0; mi < 2; mi++)
#pragma unroll
        for (int ri = 0; ri < 16; ri++) {
            int rowl = (ri & 3) + 8 * (ri >> 2) + 4 * hl;
            int m = wm + mi * 32 + rowl;
            if (m0 + m < cnt) {
                size_t hrow = (size_t)(base + m0 + m) * HID + n0;
#pragma unroll
                for (int ni = 0; ni < 2; ni++)
                    hbuf[hrow + wn + ni * 32 + r32] = f2bf(gelu_fast(acc[mi][ni][ri]));
            }
        }
}

// GEMM2: ybuf[slot] = h[slot] @ w2[e]^T   (gate applied in combine)
__global__ __launch_bounds__(256) void gemm2_kernel(
    const unsigned short* __restrict__ hbuf, const unsigned short* __restrict__ w2b,
    unsigned short* __restrict__ ybuf,
    const int4* __restrict__ tile_map, const int* __restrict__ ntiles)
{
    if ((int)blockIdx.x >= *ntiles) return;
    int4 tm = tile_map[blockIdx.x];
    int e = tm.x, m0 = tm.y, base = tm.z, cnt = tm.w;
    int n0 = blockIdx.y * 128;

    __shared__ unsigned short As[128 * 64];
    __shared__ unsigned short Bs[128 * 64];

    int tid = threadIdx.x, lane = tid & 63, wave = tid >> 6;
    int sg = tid & 7;

    const unsigned short* ap[4];
    const unsigned short* bp[4];
#pragma unroll
    for (int j = 0; j < 4; j++) {
        int r = j * 32 + (tid >> 3);
        int ai = base + m0 + r; if (m0 + r >= cnt) ai = base;
        int ss = (sg ^ sw8(r)) * 8;
        ap[j] = hbuf + (size_t)ai * HID + ss;
        bp[j] = w2b + ((size_t)e * DIM + n0 + r) * HID + ss;
    }

    int wm = (wave >> 1) * 64, wn = (wave & 1) * 64;
    int r32 = lane & 31, hl = lane >> 5;
    int aoff[2][4], boff[2][4];
#pragma unroll
    for (int mi = 0; mi < 2; mi++)
#pragma unroll
        for (int s = 0; s < 4; s++) {
            int m = wm + mi * 32 + r32;
            int seg = s * 2 + hl;
            aoff[mi][s] = m * 64 + ((seg ^ sw8(m)) * 8);
            int n = wn + mi * 32 + r32;
            boff[mi][s] = n * 64 + ((seg ^ sw8(n)) * 8);
        }

    f32x16 acc[2][2] = {};
    for (int k0 = 0; k0 < HID; k0 += 64) {
        __syncthreads();
#pragma unroll
        for (int j = 0; j < 4; j++) {
            g2l16(ap[j] + k0, &As[(j * 256 + tid) * 8]);
            g2l16(bp[j] + k0, &Bs[(j * 256 + tid) * 8]);
        }
        __syncthreads();
#pragma unroll
        for (int s = 0; s < 4; s++) {
            bf16x8 a0 = *(const bf16x8*)&As[aoff[0][s]];
            bf16x8 a1 = *(const bf16x8*)&As[aoff[1][s]];
            bf16x8 b0 = *(const bf16x8*)&Bs[boff[0][s]];
            bf16x8 b1 = *(const bf16x8*)&Bs[boff[1][s]];
            acc[0][0] = __builtin_amdgcn_mfma_f32_32x32x16_bf16(a0, b0, acc[0][0], 0, 0, 0);
            acc[0][1] = __builtin_amdgcn_mfma_f32_32x32x16_bf16(a0, b1, acc[0][1], 0, 0, 0);
            acc[1][0] = __builtin_amdgcn_mfma_f32_32x32x16_bf16(a1, b0, acc[1][0], 0, 0, 0);
            acc[1][1] = __builtin_amdgcn_mfma_f32_32x32x16_bf16(a1, b1, acc[1][1], 0, 0, 0);
        }
    }

#pragma unroll
    for (int mi = 0; mi < 2; mi++)
#pragma unroll
        for (int ri = 0; ri < 16; ri++) {
            int rowl = (ri & 3) + 8 * (ri >> 2) + 4 * hl;
            int m = wm + mi * 32 + rowl;
            if (m0 + m < cnt) {
                size_t yrow = (size_t)(base + m0 + m) * DIM + n0;
#pragma unroll
                for (int ni = 0; ni < 2; ni++)
                    ybuf[yrow + wn + ni * 32 + r32] = f2bf(acc[mi][ni][ri]);
            }
        }
}

// -------- combine: out = x + g0*y[slot0] + g1*y[slot1] --------
__global__ __launch_bounds__(256) void combine_kernel(
    const float* __restrict__ x, const unsigned short* __restrict__ ybuf,
    const int2* __restrict__ inv, const float2* __restrict__ gates,
    float* __restrict__ out)
{
    int tid = threadIdx.x;
    int wave = tid >> 6, lane = tid & 63;
    int t = blockIdx.x * 4 + wave;
    int2 sl = inv[t];
    float2 g = gates[t];
    const float* xr = x + (size_t)t * DIM;
    const unsigned short* y0 = ybuf + (size_t)sl.x * DIM;
    const unsigned short* y1 = ybuf + (size_t)sl.y * DIM;
    float* orow = out + (size_t)t * DIM;
#pragma unroll
    for (int j = 0; j < 4; j++) {
        int idx = j * 256 + lane * 4;
        float4 xv = *(const float4*)(xr + idx);
        ushort4 a = *(const ushort4*)(y0 + idx);
        ushort4 b = *(const ushort4*)(y1 + idx);
        float4 o;
        o.x = xv.x + g.x * bf2f(a.x) + g.y * bf2f(b.x);
        o.y = xv.y + g.x * bf2f(a.y) + g.y * bf2f(b.y);
        o.z = xv.z + g.x * bf2f(a.z) + g.y * bf2f(b.z);
        o.w = xv.w + g.x * bf2f(a.w) + g.y * bf2f(b.w);
        *(float4*)(orow + idx) = o;
    }
}

extern "C" void kernel_launch(void* const* d_in, const int* in_sizes, int n_in,
                              void* d_out, int out_size, void* d_ws, size_t ws_size,
                              hipStream_t stream) {
    (void)in_sizes; (void)n_in; (void)out_size; (void)ws_size;
    const float* x     = (const float*)d_in[0];
    const float* gw    = (const float*)d_in[1];
    const float* w1    = (const float*)d_in[2];
    const float* w2    = (const float*)d_in[3];
    const float* gamma = (const float*)d_in[4];
    const float* beta  = (const float*)d_in[5];
    float* out = (float*)d_out;
    char* ws = (char*)d_ws;

    unsigned short* xnb  = (unsigned short*)(ws + OFF_XN);
    unsigned short* w1b  = (unsigned short*)(ws + OFF_W1B);
    unsigned short* w2b  = (unsigned short*)(ws + OFF_W2B);
    unsigned short* hbuf = (unsigned short*)(ws + OFF_H);
    unsigned short* ybuf = (unsigned short*)(ws + OFF_W1B);  // reuse w1b after gemm1
    int*    atok    = (int*)(ws + OFF_ATOK);
    int2*   inv     = (int2*)(ws + OFF_INV);
    int*    topi    = (int*)(ws + OFF_TOPI);
    float2* gates   = (float2*)(ws + OFF_GATES);
    int*    cpart   = (int*)(ws + OFF_CPART);
    float*  ppart   = (float*)(ws + OFF_PPART);
    int*    counts  = (int*)(ws + OFF_COUNTS);
    int*    offsets = (int*)(ws + OFF_OFFS);
    int*    cnt2    = (int*)(ws + OFF_CNT2);
    int*    ntiles  = (int*)(ws + OFF_NT);
    int4*   tmap    = (int4*)(ws + OFF_TMAP);

    // zero the partial histograms (cpart+ppart contiguous 4 KB)
    hipMemsetAsync(ws + OFF_CPART, 0, 4096, stream);

    int n1 = (NE * HID * DIM) / 4, n2 = (NE * DIM * HID) / 4;
    convert_kernel<<<(n1 + n2 + 255) / 256, 256, 0, stream>>>(
        (const float4*)w1, (ushort4*)w1b, n1, (const float4*)w2, (ushort4*)w2b, n2);

    ln_router_kernel<<<T_TOK / 4, 256, 0, stream>>>(x, gw, gamma, beta, xnb, topi, gates, cpart, ppart);
    finalize_kernel<<<1, 64, 0, stream>>>(cpart, ppart, counts, offsets, cnt2, ntiles, tmap,
                                          out + (size_t)T_TOK * DIM);
    placement_kernel<<<T_TOK / 256, 256, 0, stream>>>(topi, offsets, cnt2, atok, inv);

    gemm1_kernel<<<dim3(136, HID / 128), 256, 0, stream>>>(xnb, w1b, hbuf, atok, tmap, ntiles);
    gemm2_kernel<<<dim3(136, DIM / 128), 256, 0, stream>>>(hbuf, w2b, ybuf, tmap, ntiles);
    combine_kernel<<<T_TOK / 4, 256, 0, stream>>>(x, ybuf, inv, gates, out);
}